// Round 2
// baseline (192.516 us; speedup 1.0000x reference)
//
#include <hip/hip_runtime.h>

// B=16, C=256, O=256, H=W=64, T_DIM=512, E=4, K=3
typedef __bf16 bf16x8 __attribute__((ext_vector_type(8)));
typedef float f32x4 __attribute__((ext_vector_type(4)));

#define APLANE 1040   // ushorts per A plane (128 rows x 8c = 1024, pad to 1040 -> plane stride = 8 banks mod 32)
#define BPLANE 2128   // ushorts per B plane (4h x 66w x 8c = 2112, pad to 2128 -> 8 banks mod 32)

__device__ __forceinline__ unsigned short f2bf(float f) {
  union { float f; unsigned int u; } v;
  v.f = f;
  unsigned int r = v.u + 0x7FFFu + ((v.u >> 16) & 1u);  // RNE
  return (unsigned short)(r >> 16);
}

__device__ __forceinline__ void load_lds16(const void* g, void* l) {
  __builtin_amdgcn_global_load_lds(
      (__attribute__((address_space(1))) void*)(void*)g,
      (__attribute__((address_space(3))) void*)l, 16, 0, 0);
}

// ---------- transpose + pooled partials ----------
// x[b][c][h][w] fp32 -> xT[b][h][sl=c>>3][w][c&7] bf16 ; part[b*64+h][c] = sum_w x
__global__ void transpose_kernel(const float* __restrict__ x, unsigned short* __restrict__ xT,
                                 float* __restrict__ part) {
  int bh = blockIdx.x, b = bh >> 6, h = bh & 63;
  __shared__ unsigned short lds[64 * 264];   // [w][c], pad 264 keeps 16B alignment
  __shared__ float psum[256];
  int t = threadIdx.x, lane = t & 63, wv = t >> 6;
  const float* xb = x + (size_t)b * 1048576 + h * 64;
  for (int it = 0; it < 64; ++it) {
    int c = it * 4 + wv;
    float v = xb[(size_t)c * 4096 + lane];
    lds[lane * 264 + c] = f2bf(v);
    float s = v;
    #pragma unroll
    for (int off = 32; off; off >>= 1) s += __shfl_xor(s, off);
    if (lane == 0) psum[c] = s;
  }
  __syncthreads();
  size_t ob = (size_t)bh * 16384;   // 32 slots * 64 w * 8
  #pragma unroll
  for (int it = 0; it < 8; ++it) {
    int sl = it * 4 + wv;
    uint4 u = *(const uint4*)&lds[lane * 264 + sl * 8];
    *(uint4*)&xT[ob + ((size_t)sl * 64 + lane) * 8] = u;
  }
  if (t < 256) part[(size_t)bh * 256 + t] = psum[t];
}

// ---------- router (fp32 exact) ----------
__global__ void router_kernel(
    const float* __restrict__ time_emb, const float* __restrict__ part,
    const float* __restrict__ Wq, const float* __restrict__ bq,
    const float* __restrict__ Wk, const float* __restrict__ bk,
    const float* __restrict__ Wv, const float* __restrict__ bv,
    const float* __restrict__ Wm1, const float* __restrict__ bm1,
    const float* __restrict__ Wm2, const float* __restrict__ bm2,
    const float* __restrict__ Wc, const float* __restrict__ bc,
    const float* __restrict__ expert_b,
    float* __restrict__ rw_out, float* __restrict__ beff_out) {
  int b = blockIdx.x, t = threadIdx.x;
  __shared__ float te[512], pl[256], xa[256], m1s[64], xms[256], rws[4];
  te[t] = time_emb[b * 512 + t];
  te[t + 256] = time_emb[b * 512 + 256 + t];
  {
    float s = 0.f;
    const float* pp = part + (size_t)b * 16384 + t;
    for (int hh = 0; hh < 64; ++hh) s += pp[hh * 256];
    pl[t] = s * (1.0f / 4096.0f);
  }
  __syncthreads();
  float q = bq[t], k = bk[t], v = bv[t];
  const float* wq = Wq + (size_t)t * 512;
  for (int i = 0; i < 512; ++i) q += te[i] * wq[i];
  const float* wk = Wk + (size_t)t * 256;
  const float* wv = Wv + (size_t)t * 256;
  for (int i = 0; i < 256; ++i) { float p = pl[i]; k += p * wk[i]; v += p * wv[i]; }
  float attn = 1.0f / (1.0f + expf(-(q * k)));
  float xatt = v * attn;
  xa[t] = xatt;
  __syncthreads();
  if (t < 64) {
    float s = bm1[t];
    const float* w1 = Wm1 + (size_t)t * 256;
    for (int i = 0; i < 256; ++i) s += xa[i] * w1[i];
    m1s[t] = 0.5f * s * (1.0f + erff(s * 0.7071067811865476f));
  }
  __syncthreads();
  float hsum = bm2[t];
  const float* w2 = Wm2 + (size_t)t * 64;
  for (int j = 0; j < 64; ++j) hsum += m1s[j] * w2[j];
  float xm = xatt + hsum;
  xms[t] = xm;
  __syncthreads();
  if (t < 4) {
    float s = bc[t];
    const float* wc = Wc + (size_t)t * 256;
    for (int i = 0; i < 256; ++i) s += xms[i] * wc[i];
    float r = tanhf(s);
    rws[t] = r;
    rw_out[b * 4 + t] = r;
  }
  __syncthreads();
  float be = 0.f;
  #pragma unroll
  for (int e = 0; e < 4; ++e) be += rws[e] * expert_b[e * 256 + t];
  beff_out[b * 256 + t] = be;
}

// ---------- expert mix -> wmix[b][tap][sl=c>>3][o][c&7] bf16 ----------
__global__ void wmix_kernel(const float* __restrict__ ew, const float* __restrict__ rw,
                            unsigned short* __restrict__ wmix) {
  int o = blockIdx.x & 255;
  int bh = blockIdx.x >> 8;      // 0/1 -> 8 samples each
  int c = threadIdx.x;
  __shared__ float rsh[64];
  if (c < 64) rsh[c] = rw[c];
  __syncthreads();
  float wv[4][9];
  #pragma unroll
  for (int e = 0; e < 4; ++e) {
    const float* s = ew + (((size_t)e * 256 + o) * 256 + c) * 9;
    #pragma unroll
    for (int tt = 0; tt < 9; ++tt) wv[e][tt] = s[tt];
  }
  int sl = c >> 3, cj = c & 7;
  for (int b = bh * 8; b < bh * 8 + 8; ++b) {
    float r0 = rsh[b * 4], r1 = rsh[b * 4 + 1], r2 = rsh[b * 4 + 2], r3 = rsh[b * 4 + 3];
    #pragma unroll
    for (int tt = 0; tt < 9; ++tt) {
      float m = r0 * wv[0][tt] + r1 * wv[1][tt] + r2 * wv[2][tt] + r3 * wv[3][tt];
      wmix[(((size_t)(b * 9 + tt) * 32 + sl) * 256 + o) * 8 + cj] = f2bf(m);
    }
  }
}

// ---------- conv as implicit GEMM, double-buffered, XCD-swizzled ----------
__global__ __launch_bounds__(256, 3) void conv_kernel(
    const unsigned short* __restrict__ xT, const unsigned short* __restrict__ wmix,
    const float* __restrict__ beff, float* __restrict__ out) {
  __shared__ unsigned short As[2][4 * APLANE];   // 16.6 KB
  __shared__ unsigned short Bs[2][4 * BPLANE];   // 34.0 KB
  int bid = blockIdx.x;
  // XCD swizzle: same b -> same XCD (xcd = bid & 7, 128 blocks per XCD = 2 samples)
  int b = ((bid & 7) << 1) | ((bid >> 9) & 1);
  int rem = (bid >> 3) & 63;
  int o0 = (rem >> 5) << 7;
  int h0 = (rem & 31) << 1;
  int tid = threadIdx.x;
  int wid = tid >> 6, lane = tid & 63;
  int lm = lane & 15, lg = lane >> 4;
  int wm = wid >> 1, wn = wid & 1;

  const unsigned short* xTb = xT + (size_t)b * 64 * 16384;
  const unsigned short* wmixb = wmix + (size_t)b * 9 * 32 * 2048;

  auto stageA = [&](int buf, int tap, int cc) {
    const unsigned short* src =
        wmixb + ((size_t)(tap * 32 + cc * 4 + wid) * 256 + o0) * 8 + lane * 8;
    unsigned short* dst = &As[buf][wid * APLANE];
    load_lds16(src, dst);                    // rows 0..63 of this plane
    load_lds16(src + 512, dst + 512);        // rows 64..127
  };
  auto stageB = [&](int buf, int cc) {
    int hh = h0 - 1 + wid;
    unsigned short* dstp = &Bs[buf][(wid * 66 + 1) * 8];
    if (hh >= 0 && hh < 64) {
      const unsigned short* src = xTb + (size_t)hh * 16384 + cc * 2048 + lane * 8;
      #pragma unroll
      for (int q = 0; q < 4; ++q)
        load_lds16(src + q * 512, dstp + q * BPLANE);
    } else {
      uint4 z = make_uint4(0u, 0u, 0u, 0u);
      #pragma unroll
      for (int q = 0; q < 4; ++q)
        *(uint4*)&dstp[q * BPLANE + lane * 8] = z;
    }
  };

  // zero halo columns (w=-1 -> col0, w=64 -> col65), all 4 h-rows, 4 planes, both buffers
  if (tid < 64) {
    int bufi = tid >> 5, sl = (tid >> 3) & 3, hh = (tid >> 1) & 3, cl = (tid & 1) ? 65 : 0;
    *(uint4*)&Bs[bufi][sl * BPLANE + (hh * 66 + cl) * 8] = make_uint4(0u, 0u, 0u, 0u);
  }

  f32x4 acc[4][4];
  #pragma unroll
  for (int mf = 0; mf < 4; ++mf)
    #pragma unroll
    for (int nf = 0; nf < 4; ++nf)
      acc[mf][nf] = (f32x4){0.f, 0.f, 0.f, 0.f};

  int aoff[4], boff[4];
  #pragma unroll
  for (int mf = 0; mf < 4; ++mf)
    aoff[mf] = lg * APLANE + (wm * 64 + mf * 16 + lm) * 8;
  #pragma unroll
  for (int nf = 0; nf < 4; ++nf)
    boff[nf] = lg * BPLANE + (wn * 66 + nf * 16 + lm) * 8;

  stageB(0, 0);
  stageA(0, 0, 0);
  __syncthreads();

  int abuf = 0, bbuf = 0;
  for (int cc = 0; cc < 8; ++cc) {
    #pragma unroll
    for (int tap = 0; tap < 9; ++tap) {
      // issue next-tile staging BEFORE compute (T3-minimum pattern)
      if (tap < 8) {
        stageA(abuf ^ 1, tap + 1, cc);
      } else if (cc < 7) {
        stageA(abuf ^ 1, 0, cc + 1);
        stageB(bbuf ^ 1, cc + 1);
      }
      const int kh = tap / 3, kw = tap % 3;
      bf16x8 af[4], bfr[4];
      #pragma unroll
      for (int mf = 0; mf < 4; ++mf)
        af[mf] = *(const bf16x8*)&As[abuf][aoff[mf]];
      #pragma unroll
      for (int nf = 0; nf < 4; ++nf)
        bfr[nf] = *(const bf16x8*)&Bs[bbuf][boff[nf] + (kh * 66 + kw) * 8];
      #pragma unroll
      for (int mf = 0; mf < 4; ++mf)
        #pragma unroll
        for (int nf = 0; nf < 4; ++nf)
          acc[mf][nf] = __builtin_amdgcn_mfma_f32_16x16x32_bf16(af[mf], bfr[nf], acc[mf][nf], 0, 0, 0);
      __syncthreads();   // next buffers staged (vmcnt drained), reads of cur done
      abuf ^= 1;
    }
    bbuf ^= 1;
  }

  // epilogue: C/D layout col=lane&15, row=(lane>>4)*4+reg
  float be[4][4];
  #pragma unroll
  for (int mf = 0; mf < 4; ++mf)
    #pragma unroll
    for (int r = 0; r < 4; ++r)
      be[mf][r] = beff[b * 256 + o0 + wm * 64 + mf * 16 + lg * 4 + r];
  #pragma unroll
  for (int mf = 0; mf < 4; ++mf) {
    int o = o0 + wm * 64 + mf * 16 + lg * 4;
    #pragma unroll
    for (int nf = 0; nf < 4; ++nf) {
      int p = wn * 64 + nf * 16 + lm;
      int h = h0 + (p >> 6), w = p & 63;
      float* op = out + (((size_t)(b * 256 + o)) * 64 + h) * 64 + w;
      #pragma unroll
      for (int r = 0; r < 4; ++r)
        op[(size_t)r * 4096] = acc[mf][nf][r] + be[mf][r];
    }
  }
}

extern "C" void kernel_launch(void* const* d_in, const int* in_sizes, int n_in,
                              void* d_out, int out_size, void* d_ws, size_t ws_size,
                              hipStream_t stream) {
  const float* x        = (const float*)d_in[0];
  const float* time_emb = (const float*)d_in[1];
  const float* Wq = (const float*)d_in[2];
  const float* bq = (const float*)d_in[3];
  const float* Wk = (const float*)d_in[4];
  const float* bk = (const float*)d_in[5];
  const float* Wv = (const float*)d_in[6];
  const float* bv = (const float*)d_in[7];
  const float* Wm1 = (const float*)d_in[8];
  const float* bm1 = (const float*)d_in[9];
  const float* Wm2 = (const float*)d_in[10];
  const float* bm2 = (const float*)d_in[11];
  const float* Wc = (const float*)d_in[12];
  const float* bc = (const float*)d_in[13];
  const float* expert_w = (const float*)d_in[14];
  const float* expert_b = (const float*)d_in[15];
  float* out = (float*)d_out;

  char* ws = (char*)d_ws;
  float* rw   = (float*)(ws + 0);                       // 256 B
  float* beff = (float*)(ws + 1024);                    // 16 KB
  float* part = (float*)(ws + 20480);                   // 1 MB
  unsigned short* xT   = (unsigned short*)(ws + 1069056);              // 32 MB
  unsigned short* wmix = (unsigned short*)(ws + 1069056 + 33554432);   // 18.9 MB

  transpose_kernel<<<1024, 256, 0, stream>>>(x, xT, part);
  router_kernel<<<16, 256, 0, stream>>>(time_emb, part, Wq, bq, Wk, bk, Wv, bv,
                                        Wm1, bm1, Wm2, bm2, Wc, bc, expert_b, rw, beff);
  wmix_kernel<<<512, 256, 0, stream>>>(expert_w, rw, wmix);
  conv_kernel<<<1024, 256, 0, stream>>>(xT, wmix, beff, out);
}

// Round 3
// 147.966 us; speedup vs baseline: 1.3011x; 1.3011x over previous
//
#include <hip/hip_runtime.h>

// B=16, C=256, O=256, H=W=64, T_DIM=512, E=4, K=3
typedef __bf16 bf16x8 __attribute__((ext_vector_type(8)));
typedef float f32x4 __attribute__((ext_vector_type(4)));

__device__ __forceinline__ unsigned short f2bf(float f) {
  union { float f; unsigned int u; } v;
  v.f = f;
  unsigned int r = v.u + 0x7FFFu + ((v.u >> 16) & 1u);  // RNE
  return (unsigned short)(r >> 16);
}

__device__ __forceinline__ void load_lds16(const void* g, void* l) {
  __builtin_amdgcn_global_load_lds(
      (__attribute__((address_space(1))) void*)(void*)g,
      (__attribute__((address_space(3))) void*)l, 16, 0, 0);
}

// ---------- transpose + pad + pooled partials ----------
// x[b][c][h][w] fp32 -> xTpad[b][hp=h+1][wp=w+1][c] bf16 (zero borders)
// part[(b*64+h)*256 + c] = sum_w x[b][c][h][w]
__global__ void transpose_kernel(const float* __restrict__ x, unsigned short* __restrict__ xTpad,
                                 float* __restrict__ part) {
  int bid = blockIdx.x;
  int b = bid / 66, hp = bid % 66;
  unsigned short* rowbase = xTpad + ((size_t)(b * 66 + hp)) * 66 * 256;
  int t = threadIdx.x;
  if (hp == 0 || hp == 65) {   // zero border rows: 66*256 ushorts = 2112 uint4
    uint4 z = make_uint4(0u, 0u, 0u, 0u);
    for (int i = t; i < 2112; i += 256) ((uint4*)rowbase)[i] = z;
    return;
  }
  int h = hp - 1;
  __shared__ unsigned short lds[64][264];   // [w][c], 528B rows (16B aligned)
  __shared__ float psum[256];
  const float* xb = x + ((size_t)b * 256 * 64 + h) * 64;
  int lane = t & 63;
  #pragma unroll
  for (int g = 0; g < 16; ++g) {
    int c = g * 16 + (t >> 4);
    int w0 = (t & 15) * 4;
    float4 v = *(const float4*)&xb[(size_t)c * 4096 + w0];
    lds[w0 + 0][c] = f2bf(v.x);
    lds[w0 + 1][c] = f2bf(v.y);
    lds[w0 + 2][c] = f2bf(v.z);
    lds[w0 + 3][c] = f2bf(v.w);
    float s = v.x + v.y + v.z + v.w;
    s += __shfl_xor(s, 1); s += __shfl_xor(s, 2);
    s += __shfl_xor(s, 4); s += __shfl_xor(s, 8);
    if ((lane & 15) == 0) psum[c] = s;   // unique c per (g, 16-lane group)
  }
  __syncthreads();
  // interior rows wp=1..64, plus zero wp=0,65
  #pragma unroll
  for (int p = 0; p < 8; ++p) {
    int w = p * 8 + (t >> 5);
    int seg = t & 31;
    uint4 u = *(const uint4*)&lds[w][seg * 8];
    *(uint4*)&rowbase[(w + 1) * 256 + seg * 8] = u;
  }
  if (t < 64) {
    uint4 z = make_uint4(0u, 0u, 0u, 0u);
    int row = (t >> 5) ? 65 : 0;
    *(uint4*)&rowbase[row * 256 + (t & 31) * 8] = z;
  }
  if (t < 256) part[((size_t)b * 64 + h) * 256 + t] = psum[t];
}

// ---------- router (fp32 exact) ----------
__global__ void router_kernel(
    const float* __restrict__ time_emb, const float* __restrict__ part,
    const float* __restrict__ Wq, const float* __restrict__ bq,
    const float* __restrict__ Wk, const float* __restrict__ bk,
    const float* __restrict__ Wv, const float* __restrict__ bv,
    const float* __restrict__ Wm1, const float* __restrict__ bm1,
    const float* __restrict__ Wm2, const float* __restrict__ bm2,
    const float* __restrict__ Wc, const float* __restrict__ bc,
    const float* __restrict__ expert_b,
    float* __restrict__ rw_out, float* __restrict__ beff_out) {
  int b = blockIdx.x, t = threadIdx.x;
  __shared__ float te[512], pl[256], xa[256], m1s[64], xms[256], rws[4];
  te[t] = time_emb[b * 512 + t];
  te[t + 256] = time_emb[b * 512 + 256 + t];
  {
    float s = 0.f;
    const float* pp = part + (size_t)b * 16384 + t;
    for (int hh = 0; hh < 64; ++hh) s += pp[hh * 256];
    pl[t] = s * (1.0f / 4096.0f);
  }
  __syncthreads();
  float q = bq[t], k = bk[t], v = bv[t];
  const float4* wq4 = (const float4*)(Wq + (size_t)t * 512);
  #pragma unroll 4
  for (int i = 0; i < 128; ++i) {
    float4 w4 = wq4[i];
    q += w4.x * te[i*4] + w4.y * te[i*4+1] + w4.z * te[i*4+2] + w4.w * te[i*4+3];
  }
  const float4* wk4 = (const float4*)(Wk + (size_t)t * 256);
  const float4* wv4 = (const float4*)(Wv + (size_t)t * 256);
  #pragma unroll 4
  for (int i = 0; i < 64; ++i) {
    float4 a4 = wk4[i], b4 = wv4[i];
    float p0 = pl[i*4], p1 = pl[i*4+1], p2 = pl[i*4+2], p3 = pl[i*4+3];
    k += a4.x * p0 + a4.y * p1 + a4.z * p2 + a4.w * p3;
    v += b4.x * p0 + b4.y * p1 + b4.z * p2 + b4.w * p3;
  }
  float attn = 1.0f / (1.0f + expf(-(q * k)));
  float xatt = v * attn;
  xa[t] = xatt;
  __syncthreads();
  if (t < 64) {
    float s = bm1[t];
    const float4* w1 = (const float4*)(Wm1 + (size_t)t * 256);
    #pragma unroll 4
    for (int i = 0; i < 64; ++i) {
      float4 w4 = w1[i];
      s += w4.x * xa[i*4] + w4.y * xa[i*4+1] + w4.z * xa[i*4+2] + w4.w * xa[i*4+3];
    }
    m1s[t] = 0.5f * s * (1.0f + erff(s * 0.7071067811865476f));
  }
  __syncthreads();
  float hsum = bm2[t];
  const float* w2 = Wm2 + (size_t)t * 64;
  for (int j = 0; j < 64; ++j) hsum += m1s[j] * w2[j];
  float xm = xatt + hsum;
  xms[t] = xm;
  __syncthreads();
  if (t < 4) {
    float s = bc[t];
    const float* wc = Wc + (size_t)t * 256;
    for (int i = 0; i < 256; ++i) s += xms[i] * wc[i];
    float r = tanhf(s);
    rws[t] = r;
    rw_out[b * 4 + t] = r;
  }
  __syncthreads();
  float be = 0.f;
  #pragma unroll
  for (int e = 0; e < 4; ++e) be += rws[e] * expert_b[e * 256 + t];
  beff_out[b * 256 + t] = be;
}

// ---------- expert mix -> wmix[b][o][k], k = tap*256 + c ----------
__global__ void wmix_kernel(const float* __restrict__ ew, const float* __restrict__ rw,
                            unsigned short* __restrict__ wmix) {
  int o = blockIdx.x, t = threadIdx.x;
  __shared__ float lew[4][2304];
  __shared__ float rsh[64];
  if (t < 64) rsh[t] = rw[t];
  #pragma unroll
  for (int e = 0; e < 4; ++e) {
    const float* s = ew + ((size_t)e * 256 + o) * 2304;
    #pragma unroll
    for (int j = 0; j < 9; ++j) lew[e][j * 256 + t] = s[j * 256 + t];
  }
  __syncthreads();
  float wv[4][9];
  #pragma unroll
  for (int e = 0; e < 4; ++e)
    #pragma unroll
    for (int tt = 0; tt < 9; ++tt) wv[e][tt] = lew[e][t * 9 + tt];
  for (int b = 0; b < 16; ++b) {
    float r0 = rsh[b*4], r1 = rsh[b*4+1], r2 = rsh[b*4+2], r3 = rsh[b*4+3];
    unsigned short* wo = wmix + ((size_t)b * 256 + o) * 2304 + t;
    #pragma unroll
    for (int tt = 0; tt < 9; ++tt) {
      float m = r0 * wv[0][tt] + r1 * wv[1][tt] + r2 * wv[2][tt] + r3 * wv[3][tt];
      wo[tt * 256] = f2bf(m);
    }
  }
}

// ---------- conv: 256x256x2304 GEMM per sample, 8-phase counted-vmcnt ----------
// 512 thr = 8 waves (4M x 2N). A = wmix rows o, B = xTpad im2col rows n=(hr,w).
// LDS: A,B double-buffered [2][256][64] bf16 = 128 KB. T2 swizzle via
// pre-swizzled global source (linear LDS dest) + XOR'd ds_read.
__global__ __launch_bounds__(512, 2) void conv_kernel(
    const unsigned short* __restrict__ xT, const unsigned short* __restrict__ wmix,
    const float* __restrict__ beff, float* __restrict__ out) {
  __shared__ unsigned short As[2][16384];
  __shared__ unsigned short Bs[2][16384];
  int bid = blockIdx.x;
  int b = ((bid & 7) << 1) | ((bid >> 7) & 1);   // same b -> same XCD
  int nt = (bid >> 3) & 15;
  int h0 = nt << 2;
  int tid = threadIdx.x;
  int wid = tid >> 6, lane = tid & 63;
  int lm = lane & 15, lg = lane >> 4;
  int wm = wid >> 1, wn = wid & 1;   // 4M x 2N wave grid

  const unsigned short* wmb = wmix + (size_t)b * 256 * 2304;
  const unsigned short* xTb = xT + (size_t)b * 66 * 66 * 256;

  // staging lane constants (pre-swizzled source slot)
  int lr = lane >> 3;                   // row-in-8
  int slot_g = (lane & 7) ^ lr;
  int a_lane = lr * 2304 + slot_g * 8;  // elements
  int b_lane = lr * 256 + slot_g * 8;

  // read-side swizzled k-slot offsets (ushorts)
  int sw0 = ((0 + lg) ^ (lm & 7)) * 8;
  int sw1 = ((4 + lg) ^ (lm & 7)) * 8;

  auto stA = [&](int buf, int s, int u) {
    const unsigned short* src = wmb + (size_t)(u * 64 + wid * 8) * 2304 + s * 64 + a_lane;
    load_lds16(src, &As[buf][(u * 64 + wid * 8) * 64]);
  };
  auto stB = [&](int buf, int s, int bh, int rq) {
    int tap = s >> 2;
    int kh = tap / 3, kw = tap - kh * 3;
    int c0 = (s & 3) * 64;
    const unsigned short* src =
        xTb + (size_t)((h0 + bh * 2 + rq + kh) * 66 + wid * 8 + kw) * 256 + c0 + b_lane;
    load_lds16(src, &Bs[buf][(bh * 128 + rq * 64 + wid * 8) * 64]);
  };

  f32x4 acc[4][8];
  #pragma unroll
  for (int mf = 0; mf < 4; ++mf)
    #pragma unroll
    for (int nf = 0; nf < 8; ++nf)
      acc[mf][nf] = (f32x4){0.f, 0.f, 0.f, 0.f};

  // prologue: stage tile 0 (order: L1..L6 needed at P1/P2, L7 L8 at P3)
  stA(0, 0, 0); stA(0, 0, 1); stA(0, 0, 2); stA(0, 0, 3);
  stB(0, 0, 0, 0); stB(0, 0, 1, 0);
  stB(0, 0, 0, 1); stB(0, 0, 1, 1);
  asm volatile("s_waitcnt vmcnt(2)" ::: "memory");
  __builtin_amdgcn_s_barrier();

  auto do_tile = [&](int t, int BUF) __attribute__((always_inline)) {
    bool st = (t < 35);
    int s = t + 1;
    bf16x8 a01[2][2], a23[2][2], bA[4][2], bB[4][2];
    // ---- P1: read A mf0-1 + B rows 0-63 of own half; stage (t+1) A0-A2
    #pragma unroll
    for (int mf = 0; mf < 2; ++mf) {
      a01[mf][0] = *(const bf16x8*)&As[BUF][(wm * 64 + mf * 16 + lm) * 64 + sw0];
      a01[mf][1] = *(const bf16x8*)&As[BUF][(wm * 64 + mf * 16 + lm) * 64 + sw1];
    }
    #pragma unroll
    for (int nf = 0; nf < 4; ++nf) {
      bA[nf][0] = *(const bf16x8*)&Bs[BUF][(wn * 128 + nf * 16 + lm) * 64 + sw0];
      bA[nf][1] = *(const bf16x8*)&Bs[BUF][(wn * 128 + nf * 16 + lm) * 64 + sw1];
    }
    if (st) { stA(BUF ^ 1, s, 0); stA(BUF ^ 1, s, 1); stA(BUF ^ 1, s, 2); }
    __builtin_amdgcn_s_barrier();
    asm volatile("s_waitcnt lgkmcnt(0)" ::: "memory");
    __builtin_amdgcn_sched_barrier(0);
    __builtin_amdgcn_s_setprio(1);
    #pragma unroll
    for (int mf = 0; mf < 2; ++mf)
      #pragma unroll
      for (int nf = 0; nf < 4; ++nf)
        #pragma unroll
        for (int kk = 0; kk < 2; ++kk)
          acc[mf][nf] = __builtin_amdgcn_mfma_f32_16x16x32_bf16(a01[mf][kk], bA[nf][kk], acc[mf][nf], 0, 0, 0);
    __builtin_amdgcn_s_setprio(0);
    __builtin_amdgcn_s_barrier();
    // ---- P2: read A mf2-3; stage A3,B(h0,r0),B(h1,r0); vmcnt(6)
    #pragma unroll
    for (int mf = 0; mf < 2; ++mf) {
      a23[mf][0] = *(const bf16x8*)&As[BUF][(wm * 64 + (mf + 2) * 16 + lm) * 64 + sw0];
      a23[mf][1] = *(const bf16x8*)&As[BUF][(wm * 64 + (mf + 2) * 16 + lm) * 64 + sw1];
    }
    if (st) { stA(BUF ^ 1, s, 3); stB(BUF ^ 1, s, 0, 0); stB(BUF ^ 1, s, 1, 0); }
    if (st) { asm volatile("s_waitcnt vmcnt(6)" ::: "memory"); }
    else    { asm volatile("s_waitcnt vmcnt(0)" ::: "memory"); }
    __builtin_amdgcn_s_barrier();
    asm volatile("s_waitcnt lgkmcnt(0)" ::: "memory");
    __builtin_amdgcn_sched_barrier(0);
    __builtin_amdgcn_s_setprio(1);
    #pragma unroll
    for (int mf = 0; mf < 2; ++mf)
      #pragma unroll
      for (int nf = 0; nf < 4; ++nf)
        #pragma unroll
        for (int kk = 0; kk < 2; ++kk)
          acc[mf + 2][nf] = __builtin_amdgcn_mfma_f32_16x16x32_bf16(a23[mf][kk], bA[nf][kk], acc[mf + 2][nf], 0, 0, 0);
    __builtin_amdgcn_s_setprio(0);
    __builtin_amdgcn_s_barrier();
    // ---- P3: read B rows 64-127 of own half; stage B(h0,r1)
    #pragma unroll
    for (int nf = 0; nf < 4; ++nf) {
      bB[nf][0] = *(const bf16x8*)&Bs[BUF][(wn * 128 + 64 + nf * 16 + lm) * 64 + sw0];
      bB[nf][1] = *(const bf16x8*)&Bs[BUF][(wn * 128 + 64 + nf * 16 + lm) * 64 + sw1];
    }
    if (st) stB(BUF ^ 1, s, 0, 1);
    __builtin_amdgcn_s_barrier();
    asm volatile("s_waitcnt lgkmcnt(0)" ::: "memory");
    __builtin_amdgcn_sched_barrier(0);
    __builtin_amdgcn_s_setprio(1);
    #pragma unroll
    for (int mf = 0; mf < 2; ++mf)
      #pragma unroll
      for (int nf = 0; nf < 4; ++nf)
        #pragma unroll
        for (int kk = 0; kk < 2; ++kk)
          acc[mf + 2][nf + 4] = __builtin_amdgcn_mfma_f32_16x16x32_bf16(a23[mf][kk], bB[nf][kk], acc[mf + 2][nf + 4], 0, 0, 0);
    __builtin_amdgcn_s_setprio(0);
    __builtin_amdgcn_s_barrier();
    // ---- P4: stage B(h1,r1); vmcnt(2) protects next tile's P1/P2 reads
    if (st) stB(BUF ^ 1, s, 1, 1);
    asm volatile("s_waitcnt vmcnt(2)" ::: "memory");
    __builtin_amdgcn_s_barrier();
    __builtin_amdgcn_s_setprio(1);
    #pragma unroll
    for (int mf = 0; mf < 2; ++mf)
      #pragma unroll
      for (int nf = 0; nf < 4; ++nf)
        #pragma unroll
        for (int kk = 0; kk < 2; ++kk)
          acc[mf][nf + 4] = __builtin_amdgcn_mfma_f32_16x16x32_bf16(a01[mf][kk], bB[nf][kk], acc[mf][nf + 4], 0, 0, 0);
    __builtin_amdgcn_s_setprio(0);
    __builtin_amdgcn_s_barrier();
  };

  for (int th = 0; th < 18; ++th) {
    do_tile(2 * th, 0);
    do_tile(2 * th + 1, 1);
  }

  // epilogue: D row (o) = lg*4 + reg, col (n) = lm
  #pragma unroll
  for (int mf = 0; mf < 4; ++mf) {
    int o = wm * 64 + mf * 16 + lg * 4;
    float be0 = beff[b * 256 + o + 0];
    float be1 = beff[b * 256 + o + 1];
    float be2 = beff[b * 256 + o + 2];
    float be3 = beff[b * 256 + o + 3];
    #pragma unroll
    for (int nf = 0; nf < 8; ++nf) {
      int n = wn * 128 + nf * 16 + lm;
      int hh = h0 + (n >> 6), w = n & 63;
      float* op = out + (((size_t)(b * 256 + o)) * 64 + hh) * 64 + w;
      op[0]            = acc[mf][nf][0] + be0;
      op[4096]         = acc[mf][nf][1] + be1;
      op[2 * 4096]     = acc[mf][nf][2] + be2;
      op[3 * 4096]     = acc[mf][nf][3] + be3;
    }
  }
}

extern "C" void kernel_launch(void* const* d_in, const int* in_sizes, int n_in,
                              void* d_out, int out_size, void* d_ws, size_t ws_size,
                              hipStream_t stream) {
  const float* x        = (const float*)d_in[0];
  const float* time_emb = (const float*)d_in[1];
  const float* Wq = (const float*)d_in[2];
  const float* bq = (const float*)d_in[3];
  const float* Wk = (const float*)d_in[4];
  const float* bk = (const float*)d_in[5];
  const float* Wv = (const float*)d_in[6];
  const float* bv = (const float*)d_in[7];
  const float* Wm1 = (const float*)d_in[8];
  const float* bm1 = (const float*)d_in[9];
  const float* Wm2 = (const float*)d_in[10];
  const float* bm2 = (const float*)d_in[11];
  const float* Wc = (const float*)d_in[12];
  const float* bc = (const float*)d_in[13];
  const float* expert_w = (const float*)d_in[14];
  const float* expert_b = (const float*)d_in[15];
  float* out = (float*)d_out;

  char* ws = (char*)d_ws;
  float* rw   = (float*)(ws + 0);                        // 256 B
  float* beff = (float*)(ws + 1024);                     // 16 KB
  float* part = (float*)(ws + 20480);                    // 1 MB
  unsigned short* xTpad = (unsigned short*)(ws + 1069056);             // 35.7 MB
  unsigned short* wmix  = (unsigned short*)(ws + 1069056 + 35684352);  // 18.9 MB

  transpose_kernel<<<1056, 256, 0, stream>>>(x, xTpad, part);
  router_kernel<<<16, 256, 0, stream>>>(time_emb, part, Wq, bq, Wk, bk, Wv, bv,
                                        Wm1, bm1, Wm2, bm2, Wc, bc, expert_b, rw, beff);
  wmix_kernel<<<256, 256, 0, stream>>>(expert_w, rw, wmix);
  conv_kernel<<<256, 512, 0, stream>>>(xTpad, wmix, beff, out);
}